// Round 8
// baseline (184.509 us; speedup 1.0000x reference)
//
#include <hip/hip_runtime.h>

typedef unsigned short u16;
typedef unsigned int   u32;

#define N_NODES 10000
#define N_EDGES 80000

// MFMA fragment types (per cdna4 guide: 8 bf16 in 4 VGPRs as short vector)
typedef __attribute__((ext_vector_type(8))) short bf16x8;
typedef __attribute__((ext_vector_type(4))) float fx4;
#define MFMA16(a, b, c) __builtin_amdgcn_mfma_f32_16x16x32_bf16(a, b, c, 0, 0, 0)

// ---------- bf16 helpers (round-to-nearest-even) ----------
__device__ __forceinline__ u16 f2bf(float f) {
    union { float f; u32 i; } c; c.f = f;
    u32 u = c.i;
    u32 r = (u + 0x7fffu + ((u >> 16) & 1u)) >> 16;
    return (u16)r;
}
__device__ __forceinline__ float bf2f(u16 u) {
    union { u32 i; float f; } c; c.i = ((u32)u) << 16; return c.f;
}
__device__ __forceinline__ void unpack8(uint4 w, float* v) {
    union { u32 i; float f; } c;
    c.i = w.x << 16; v[0] = c.f; c.i = w.x & 0xffff0000u; v[1] = c.f;
    c.i = w.y << 16; v[2] = c.f; c.i = w.y & 0xffff0000u; v[3] = c.f;
    c.i = w.z << 16; v[4] = c.f; c.i = w.z & 0xffff0000u; v[5] = c.f;
    c.i = w.w << 16; v[6] = c.f; c.i = w.w & 0xffff0000u; v[7] = c.f;
}

// Wave-local sync: per-wave slabs need no s_barrier. DS ops complete in
// order within a wave; lgkmcnt(0) + scheduling barrier gives the ordering.
__device__ __forceinline__ void wsync() {
    asm volatile("s_waitcnt lgkmcnt(0)" ::: "memory");
    __builtin_amdgcn_wave_barrier();
}

// =====================================================================
// MFMA helpers (16x16x32_bf16, layouts m89/m91-verified):
//   A[m][k]: lane l holds m=l&15, k=(l>>4)*8+j
//   B[k][n]: lane l holds n=l&15, k=(l>>4)*8+j  (B operand = W row-major)
//   D[r][c]: lane l holds c=l&15, r=(l>>4)*4+reg
// 3-pass split precision: v = hi + lo (both bf16); D = al*bh + ah*bl + ah*bh
// -> fp32-equivalent GEMM error (lo*lo term ~2^-18 rel, dropped).
// =====================================================================

__device__ __forceinline__ void stage_w(const float* src, int rstride,
                                        u16* wh, u16* wl, int t) {
    const int row = t >> 2, seg = t & 3;
    const float* p = src + (long)row * rstride + seg * 16;
    float v[16];
    #pragma unroll
    for (int q = 0; q < 4; ++q) *(float4*)&v[q * 4] = *(const float4*)(p + q * 4);
    u16 hh[16], ll[16];
    #pragma unroll
    for (int j = 0; j < 16; ++j) {
        u16 hi = f2bf(v[j]);
        hh[j] = hi;
        ll[j] = f2bf(v[j] - bf2f(hi));
    }
    const int base = row * 72 + seg * 16;
    *(uint4*)&wh[base]     = *(uint4*)&hh[0];
    *(uint4*)&wh[base + 8] = *(uint4*)&hh[8];
    *(uint4*)&wl[base]     = *(uint4*)&ll[0];
    *(uint4*)&wl[base + 8] = *(uint4*)&ll[8];
}

__device__ __forceinline__ void load_a64(const float* m, int arow, int ko,
                                         bf16x8 ah[2], bf16x8 al[2]) {
    if (arow < N_NODES) {
        #pragma unroll
        for (int ks = 0; ks < 2; ++ks) {
            const float* p = m + (long)arow * 64 + ks * 32 + ko;
            float v[8];
            *(float4*)&v[0] = *(const float4*)p;
            *(float4*)&v[4] = *(const float4*)(p + 4);
            #pragma unroll
            for (int j = 0; j < 8; ++j) {
                u16 hi = f2bf(v[j]);
                ah[ks][j] = (short)hi;
                al[ks][j] = (short)f2bf(v[j] - bf2f(hi));
            }
        }
    } else {
        #pragma unroll
        for (int ks = 0; ks < 2; ++ks) { ah[ks] = (bf16x8)0; al[ks] = (bf16x8)0; }
    }
}

__device__ __forceinline__ fx4 gemm3(const bf16x8 ah[2], const bf16x8 al[2],
                                     const u16* wh, const u16* wl,
                                     int colrow, int ko) {
    fx4 acc = {0.f, 0.f, 0.f, 0.f};
    #pragma unroll
    for (int ks = 0; ks < 2; ++ks) {
        const bf16x8 bh = *(const bf16x8*)&wh[colrow * 72 + ks * 32 + ko];
        const bf16x8 bl = *(const bf16x8*)&wl[colrow * 72 + ks * 32 + ko];
        acc = MFMA16(al[ks], bh, acc);
        acc = MFMA16(ah[ks], bl, acc);
        acc = MFMA16(ah[ks], bh, acc);
    }
    return acc;
}

// =====================================================================
// proj: grid (157, 8) — head h per block. One A-tile staging feeds FOUR
// GEMMs: NQ (fp32 out), NK (bf16), NV->LDS, G = NV@Wlin_h^T (bf16).
// =====================================================================
__global__ __launch_bounds__(256) void proj_kernel(
    const float* __restrict__ x,
    const float* __restrict__ Wq, const float* __restrict__ bq,
    const float* __restrict__ Wk, const float* __restrict__ bk,
    const float* __restrict__ Wv, const float* __restrict__ bv,
    const float* __restrict__ Wlin,
    float* __restrict__ NQ, u16* __restrict__ NK, u16* __restrict__ G)
{
    __shared__ __align__(16) u16 wh[64 * 72];
    __shared__ __align__(16) u16 wl[64 * 72];
    __shared__ __align__(16) u16 nvh[4 * 16 * 72];
    __shared__ __align__(16) u16 nvl[4 * 16 * 72];

    const int t  = threadIdx.x;
    const int l  = t & 63, w = t >> 6;
    const int ko = (l >> 4) * 8;
    const int r0 = blockIdx.x * 64;
    const int h  = blockIdx.y;
    const int c0 = h * 64;

    bf16x8 ah[2], al[2];
    load_a64(x, r0 + w * 16 + (l & 15), ko, ah, al);

    fx4 acc[4];

    // ---- Q panel (fp32 out) ----
    stage_w(Wq + (long)c0 * 64, 64, wh, wl, t);
    __syncthreads();
    #pragma unroll
    for (int cf = 0; cf < 4; ++cf)
        acc[cf] = gemm3(ah, al, wh, wl, cf * 16 + (l & 15), ko);
    #pragma unroll
    for (int cf = 0; cf < 4; ++cf) {
        const int col = c0 + cf * 16 + (l & 15);
        const float bias = bq[col];
        #pragma unroll
        for (int j = 0; j < 4; ++j) {
            const int gr = r0 + w * 16 + (l >> 4) * 4 + j;
            if (gr < N_NODES) NQ[(long)gr * 512 + col] = acc[cf][j] + bias;
        }
    }
    __syncthreads();

    // ---- K panel (bf16 out) ----
    stage_w(Wk + (long)c0 * 64, 64, wh, wl, t);
    __syncthreads();
    #pragma unroll
    for (int cf = 0; cf < 4; ++cf)
        acc[cf] = gemm3(ah, al, wh, wl, cf * 16 + (l & 15), ko);
    #pragma unroll
    for (int cf = 0; cf < 4; ++cf) {
        const int col = c0 + cf * 16 + (l & 15);
        const float bias = bk[col];
        #pragma unroll
        for (int j = 0; j < 4; ++j) {
            const int gr = r0 + w * 16 + (l >> 4) * 4 + j;
            if (gr < N_NODES) NK[(long)gr * 512 + col] = f2bf(acc[cf][j] + bias);
        }
    }
    __syncthreads();

    // ---- V panel -> LDS (hi/lo bf16, this wave's own 16-row slab) ----
    stage_w(Wv + (long)c0 * 64, 64, wh, wl, t);
    __syncthreads();
    #pragma unroll
    for (int cf = 0; cf < 4; ++cf)
        acc[cf] = gemm3(ah, al, wh, wl, cf * 16 + (l & 15), ko);
    #pragma unroll
    for (int cf = 0; cf < 4; ++cf) {
        const int col = cf * 16 + (l & 15);
        const float bias = bv[c0 + col];
        #pragma unroll
        for (int j = 0; j < 4; ++j) {
            const int rloc = (l >> 4) * 4 + j;
            float v = acc[cf][j] + bias;
            u16 hi = f2bf(v);
            nvh[w * 1152 + rloc * 72 + col] = hi;
            nvl[w * 1152 + rloc * 72 + col] = f2bf(v - bf2f(hi));
        }
    }
    __syncthreads();
    stage_w(Wlin + c0, 512, wh, wl, t);
    __syncthreads();

    bf16x8 a2h[2], a2l[2];
    #pragma unroll
    for (int ks = 0; ks < 2; ++ks) {
        a2h[ks] = *(const bf16x8*)&nvh[w * 1152 + (l & 15) * 72 + ks * 32 + ko];
        a2l[ks] = *(const bf16x8*)&nvl[w * 1152 + (l & 15) * 72 + ks * 32 + ko];
    }
    #pragma unroll
    for (int cf = 0; cf < 4; ++cf)
        acc[cf] = gemm3(a2h, a2l, wh, wl, cf * 16 + (l & 15), ko);

    #pragma unroll
    for (int cf = 0; cf < 4; ++cf) {
        const int col = c0 + cf * 16 + (l & 15);
        #pragma unroll
        for (int j = 0; j < 4; ++j) {
            const int gr = r0 + w * 16 + (l >> 4) * 4 + j;
            if (gr < N_NODES) G[(long)gr * 512 + col] = f2bf(acc[cf][j]);
        }
    }
}

// =====================================================================
// node kernel R28: 256 threads = 4 waves, TWO NODES PER WAVE (grid 1250;
// 10000 = 1250*8 exactly). Waves are >90% latency-stalled (R7: all
// counters low, ~45Kcy/block for ~2K instr) -> double the independent
// work per wave and pipeline it:
//  - node B's K-gather/Q-row/ef loads are issued right after phase 8A
//    where gregA dies (registers REUSED -> peak VGPR ~= R27's, <=128).
//  - B's latency hides under phase 9A + restage; B runs with ZERO block
//    barriers (wave-synchronous, private slab).
//  - weights (48 regs), `well`, B1 barrier amortized over 2 nodes.
// =====================================================================
#define SLAB_F 2272
__global__ __launch_bounds__(256) void node_kernel(
    const float* __restrict__ ef, const int* __restrict__ e1,
    const float* __restrict__ NQ, const u16* __restrict__ NK,
    const u16* __restrict__ G,
    const float* __restrict__ Weq, const float* __restrict__ beq,
    const float* __restrict__ Wev, const float* __restrict__ bev,
    const float* __restrict__ Wek, const float* __restrict__ bek,
    const float* __restrict__ Wel, const float* __restrict__ bel,
    const float* __restrict__ Wele, const float* __restrict__ bele,
    const float* __restrict__ blin,
    float* __restrict__ out_node, float* __restrict__ out_edge)
{
    __shared__ __align__(16) float well[8 * 68];           // shared across waves
    __shared__ __align__(16) float slabs[4][SLAB_F];       // per-wave

    const int t   = threadIdx.x;
    const int t64 = t & 63;
    const int wv  = t >> 6;
    const int nA  = (int)__builtin_amdgcn_readfirstlane(blockIdx.x * 8 + wv * 2);
    const int nB  = nA + 1;

    float* S      = slabs[wv];
    // phases 2-6 region (dead before gbuf at 8): eqb/ekb/sl/efl
    float* eqb    = S;             // 544 floats, pitch 68 (eob aliases)
    float* ekb    = S + 544;       // 544
    float* eob    = eqb;           // alias: eq dead after phase 3
    float* sl     = S + 1088;      // 288 floats [eh][72]
    float* efl    = S + 1376;      // 128   (inside gbuf span -> restage per node)
    u16*   gbuf   = (u16*)S;       // 8 rows x pitch 520 u16 = 8320 B = 2080 f
    float* sqk_l  = S + 2080;      // 64  (outside gbuf span)
    float* emb_l  = S + 2144;      // 64
    float* attn_l = S + 2208;      // 64   (total 2272)

    // -------- phase 0: loads for node A (+ B's edge targets) --------
    int tgA[8], tgB[8];
    #pragma unroll
    for (int i = 0; i < 8; ++i) { tgA[i] = e1[nA * 8 + i]; tgB[i] = e1[nB * 8 + i]; }

    float q8[8];
    {
        const float4* p = (const float4*)(NQ + (long)nA * 512 + t64 * 8);
        *(float4*)&q8[0] = p[0];
        *(float4*)&q8[4] = p[1];
    }
    uint4 kreg[8];
    #pragma unroll
    for (int i = 0; i < 8; ++i)
        kreg[i] = *(const uint4*)(NK + (long)tgA[i] * 512 + t64 * 8);

    float2 efv = ((const float2*)(ef + (long)nA * 128))[t64];

    float wq16[16], wv16[16], wk8[8], wele8[8];
    {
        const float4* p = (const float4*)(Weq + t64 * 16);
        #pragma unroll
        for (int q4 = 0; q4 < 4; ++q4) *(float4*)&wq16[q4 * 4] = p[q4];
        const float4* q = (const float4*)(Wev + t64 * 16);
        #pragma unroll
        for (int q4 = 0; q4 < 4; ++q4) *(float4*)&wv16[q4 * 4] = q[q4];
        const float4* r = (const float4*)(Wek + t64 * 8);
        *(float4*)&wk8[0] = r[0]; *(float4*)&wk8[4] = r[1];
        const float4* s = (const float4*)(Wele + (t64 & 15) * 8);
        *(float4*)&wele8[0] = s[0]; *(float4*)&wele8[4] = s[1];
    }
    const float beqv = beq[t64], bevv = bev[t64], bekv = bek[t64];
    const float bele_t = bele[t64 & 15];
    const float blin_t = blin[t64];

    // stage well (all 256 threads) and eflA (per-wave)
    #pragma unroll
    for (int rep = 0; rep < 2; ++rep) {
        const int idx = rep * 256 + t;
        well[(idx >> 6) * 68 + (idx & 63)] = Wel[idx];
    }
    efl[2 * t64] = efv.x; efl[2 * t64 + 1] = efv.y;

    // -------- sq butterfly (regs only) -> sqk_l --------
    auto sq_butterfly = [&]() {
        float part[8];
        #pragma unroll
        for (int i = 0; i < 8; ++i) {
            float kv[8]; unpack8(kreg[i], kv);
            part[i] = q8[0] * kv[0] + q8[1] * kv[1] + q8[2] * kv[2] + q8[3] * kv[3]
                    + q8[4] * kv[4] + q8[5] * kv[5] + q8[6] * kv[6] + q8[7] * kv[7];
        }
        #pragma unroll
        for (int m = 1; m <= 4; m <<= 1) {
            #pragma unroll
            for (int i = 0; i < 8; ++i) part[i] += __shfl_xor(part[i], m);
        }
        const int h8 = t64 >> 3, dc = t64 & 7;
        sqk_l[dc * 8 + h8] = part[dc] * 0.125f;   // sq[edge=dc][head=h8]
    };

    // -------- phases 2..8 for one node (wave-synchronous) --------
    // issues the G gather internally (after PV) and stages gbuf in phase 8.
    auto phases2to8 = [&](int n, const int* tg) {
        // phase 2: edge projections -> eq/ek LDS, ev in regs
        float ev_reg[8];
        #pragma unroll
        for (int i = 0; i < 8; ++i) {
            float aq = beqv, av = bevv;
            #pragma unroll
            for (int q = 0; q < 4; ++q) {
                float4 f = *(const float4*)&efl[i * 16 + q * 4];
                aq += f.x * wq16[q * 4] + f.y * wq16[q * 4 + 1] + f.z * wq16[q * 4 + 2] + f.w * wq16[q * 4 + 3];
                av += f.x * wv16[q * 4] + f.y * wv16[q * 4 + 1] + f.z * wv16[q * 4 + 2] + f.w * wv16[q * 4 + 3];
            }
            float ak = bekv;
            #pragma unroll
            for (int q = 0; q < 2; ++q) {
                float4 s = *(const float4*)&sqk_l[i * 8 + q * 4];
                ak += s.x * wk8[q * 4] + s.y * wk8[q * 4 + 1] + s.z * wk8[q * 4 + 2] + s.w * wk8[q * 4 + 3];
            }
            eqb[i * 68 + t64] = aq; ekb[i * 68 + t64] = ak;
            ev_reg[i] = av;
        }
        wsync();

        // phase 3: pair scores -> sl[eh][i*8+j]
        {
            const int i = t64 >> 3, j = t64 & 7;
            #pragma unroll
            for (int eh = 0; eh < 4; ++eh) {
                float acc = 0.f;
                #pragma unroll
                for (int q = 0; q < 4; ++q) {
                    float4 a = *(const float4*)&eqb[i * 68 + eh * 16 + q * 4];
                    float4 b = *(const float4*)&ekb[j * 68 + eh * 16 + q * 4];
                    acc += a.x * b.x + a.y * b.y + a.z * b.z + a.w * b.w;
                }
                sl[eh * 72 + i * 8 + j] = acc * 0.25f;
            }
        }
        wsync();

        // phase 4: softmax over j per (i, eh)
        if (t64 < 32) {
            const int i = t64 >> 2, eh = t64 & 3;
            float4 v0 = *(const float4*)&sl[eh * 72 + i * 8];
            float4 v1 = *(const float4*)&sl[eh * 72 + i * 8 + 4];
            float mx = fmaxf(fmaxf(fmaxf(v0.x, v0.y), fmaxf(v0.z, v0.w)),
                             fmaxf(fmaxf(v1.x, v1.y), fmaxf(v1.z, v1.w)));
            float e0 = __expf(v0.x - mx), e1_ = __expf(v0.y - mx);
            float e2 = __expf(v0.z - mx), e3  = __expf(v0.w - mx);
            float e4 = __expf(v1.x - mx), e5  = __expf(v1.y - mx);
            float e6 = __expf(v1.z - mx), e7  = __expf(v1.w - mx);
            float inv = 1.f / (e0 + e1_ + e2 + e3 + e4 + e5 + e6 + e7 + 1e-16f);
            float4 w0 = {e0 * inv, e1_ * inv, e2 * inv, e3 * inv};
            float4 w1 = {e4 * inv, e5 * inv, e6 * inv, e7 * inv};
            *(float4*)&sl[eh * 72 + i * 8]     = w0;
            *(float4*)&sl[eh * 72 + i * 8 + 4] = w1;
        }
        wsync();

        // phase 5: PV -> eob (ev from regs; aliases eqb)
        {
            const int eh = t64 >> 4;
            #pragma unroll
            for (int i = 0; i < 8; ++i) {
                float4 s0 = *(const float4*)&sl[eh * 72 + i * 8];
                float4 s1 = *(const float4*)&sl[eh * 72 + i * 8 + 4];
                float acc = s0.x * ev_reg[0] + s0.y * ev_reg[1]
                          + s0.z * ev_reg[2] + s0.w * ev_reg[3]
                          + s1.x * ev_reg[4] + s1.y * ev_reg[5]
                          + s1.z * ev_reg[6] + s1.w * ev_reg[7];
                eob[i * 68 + t64] = acc;
            }
        }
        wsync();

        // issue G-row gather (overlaps phases 6-8)
        uint4 greg[8];
        {
            const int i = t64 >> 3, c8 = t64 & 7;
            const uint4* gp = (const uint4*)(G + (long)tg[i] * 512);
            #pragma unroll
            for (int q = 0; q < 8; ++q) greg[q] = gp[c8 + q * 8];
        }

        // phase 6: emb[i][h]
        {
            const int i = t64 >> 3, h = t64 & 7;
            float acc = bel[h];
            #pragma unroll
            for (int q = 0; q < 16; ++q) {
                float4 a  = *(const float4*)&eob[i * 68 + q * 4];
                float4 ww = *(const float4*)&well[h * 68 + q * 4];
                acc += a.x * ww.x + a.y * ww.y + a.z * ww.z + a.w * ww.w;
            }
            emb_l[i * 8 + h] = acc;
        }
        wsync();   // phases 2-6 region dead -> gbuf may overwrite

        // phase 7: out_edge
        #pragma unroll
        for (int rep = 0; rep < 2; ++rep) {
            const int idx = rep * 64 + t64;
            const int i = idx >> 4;
            float acc = bele_t;
            #pragma unroll
            for (int h = 0; h < 8; ++h) acc += emb_l[i * 8 + h] * wele8[h];
            out_edge[(long)n * 128 + idx] = acc;
        }

        // phase 8: node attn softmax + gbuf stage (greg dies here)
        if (t64 < 8) {
            const int h = t64;
            float lg[8], mx = -1e30f;
            #pragma unroll
            for (int i = 0; i < 8; ++i) { lg[i] = emb_l[i * 8 + h] + sqk_l[i * 8 + h]; mx = fmaxf(mx, lg[i]); }
            float sum = 0.f;
            #pragma unroll
            for (int i = 0; i < 8; ++i) { float e = __expf(lg[i] - mx); attn_l[i * 8 + h] = e; sum += e; }
            float inv = 1.f / (sum + 1e-16f);
            #pragma unroll
            for (int i = 0; i < 8; ++i) attn_l[i * 8 + h] *= inv;
        }
        {
            const int i = t64 >> 3, c8 = t64 & 7;
            #pragma unroll
            for (int q = 0; q < 8; ++q)
                *(uint4*)&gbuf[i * 520 + (c8 + q * 8) * 8] = greg[q];
        }
        wsync();
    };

    // -------- phase 9: out_node from gbuf --------
    auto phase9 = [&](int n) {
        float acc = blin_t;
        #pragma unroll
        for (int i = 0; i < 8; ++i) {
            float4 a0 = *(const float4*)&attn_l[i * 8];
            float4 a1 = *(const float4*)&attn_l[i * 8 + 4];
            const u16* gr = &gbuf[i * 520];
            acc += a0.x * bf2f(gr[0 * 64 + t64]) + a0.y * bf2f(gr[1 * 64 + t64])
                 + a0.z * bf2f(gr[2 * 64 + t64]) + a0.w * bf2f(gr[3 * 64 + t64])
                 + a1.x * bf2f(gr[4 * 64 + t64]) + a1.y * bf2f(gr[5 * 64 + t64])
                 + a1.z * bf2f(gr[6 * 64 + t64]) + a1.w * bf2f(gr[7 * 64 + t64]);
        }
        out_node[(long)n * 64 + t64] = acc;
    };

    // ================= node A =================
    sq_butterfly();            // kreg/q8 = A
    __syncthreads();           // B1: well, eflA, sqk_lA visible

    phases2to8(nA, tgA);

    // issue node B's loads NOW: gregA just died in phase 8A -> registers
    // reused; latency hides under phase 9A + restage + butterfly.
    {
        const float4* p = (const float4*)(NQ + (long)nB * 512 + t64 * 8);
        *(float4*)&q8[0] = p[0];
        *(float4*)&q8[4] = p[1];
        #pragma unroll
        for (int i = 0; i < 8; ++i)
            kreg[i] = *(const uint4*)(NK + (long)tgB[i] * 512 + t64 * 8);
        efv = ((const float2*)(ef + (long)nB * 128))[t64];
    }

    phase9(nA);

    // ================= node B (no block barriers) =================
    wsync();                           // gbufA reads done before efl restage
    efl[2 * t64] = efv.x; efl[2 * t64 + 1] = efv.y;
    sq_butterfly();                    // kreg/q8 = B -> sqk_lB
    wsync();                           // eflB/sqk_lB visible (wave-local)

    phases2to8(nB, tgB);
    phase9(nB);
}

extern "C" void kernel_launch(void* const* d_in, const int* in_sizes, int n_in,
                              void* d_out, int out_size, void* d_ws, size_t ws_size,
                              hipStream_t stream) {
    (void)in_sizes; (void)n_in; (void)out_size; (void)ws_size;
    const float* x    = (const float*)d_in[0];
    const float* ef   = (const float*)d_in[1];
    const float* Wq   = (const float*)d_in[2];
    const float* bq   = (const float*)d_in[3];
    const float* Wk   = (const float*)d_in[4];
    const float* bk   = (const float*)d_in[5];
    const float* Wv   = (const float*)d_in[6];
    const float* bv   = (const float*)d_in[7];
    const float* Wlin = (const float*)d_in[8];
    const float* blin = (const float*)d_in[9];
    const float* Weq  = (const float*)d_in[10];
    const float* beq  = (const float*)d_in[11];
    const float* Wev  = (const float*)d_in[12];
    const float* bev  = (const float*)d_in[13];
    const float* Wek  = (const float*)d_in[14];
    const float* bek  = (const float*)d_in[15];
    const float* Wel  = (const float*)d_in[16];
    const float* bel  = (const float*)d_in[17];
    const float* Wele = (const float*)d_in[18];
    const float* bele = (const float*)d_in[19];
    const int* edge_index = (const int*)d_in[20];
    const int* e1 = edge_index + N_EDGES;   // row1 = targets

    float* out_node = (float*)d_out;            // N x 64 fp32
    float* out_edge = (float*)d_out + 640000;   // E x 16 fp32

    // ws: NK bf16 [0,10.24MB) | G bf16 [10.24,20.48) | NQ fp32 [20.48,40.96MB)
    char* ws = (char*)d_ws;
    u16*   NK = (u16*)ws;
    u16*   G  = (u16*)(ws + 10240000);
    float* NQ = (float*)(ws + 20480000);

    proj_kernel<<<dim3(157, 8), 256, 0, stream>>>(x, Wq, bq, Wk, bk, Wv, bv, Wlin,
                                                  NQ, NK, G);
    node_kernel<<<1250, 256, 0, stream>>>(ef, e1, NQ, NK, G,
                                          Weq, beq, Wev, bev, Wek, bek,
                                          Wel, bel, Wele, bele, blin,
                                          out_node, out_edge);
}

// Round 9
// 161.456 us; speedup vs baseline: 1.1428x; 1.1428x over previous
//
#include <hip/hip_runtime.h>

typedef unsigned short u16;
typedef unsigned int   u32;

#define N_NODES 10000
#define N_EDGES 80000

// MFMA fragment types (per cdna4 guide: 8 bf16 in 4 VGPRs as short vector)
typedef __attribute__((ext_vector_type(8))) short bf16x8;
typedef __attribute__((ext_vector_type(4))) float fx4;
#define MFMA16(a, b, c) __builtin_amdgcn_mfma_f32_16x16x32_bf16(a, b, c, 0, 0, 0)

// ---------- bf16 helpers (round-to-nearest-even) ----------
__device__ __forceinline__ u16 f2bf(float f) {
    union { float f; u32 i; } c; c.f = f;
    u32 u = c.i;
    u32 r = (u + 0x7fffu + ((u >> 16) & 1u)) >> 16;
    return (u16)r;
}
__device__ __forceinline__ float bf2f(u16 u) {
    union { u32 i; float f; } c; c.i = ((u32)u) << 16; return c.f;
}
__device__ __forceinline__ void unpack8(uint4 w, float* v) {
    union { u32 i; float f; } c;
    c.i = w.x << 16; v[0] = c.f; c.i = w.x & 0xffff0000u; v[1] = c.f;
    c.i = w.y << 16; v[2] = c.f; c.i = w.y & 0xffff0000u; v[3] = c.f;
    c.i = w.z << 16; v[4] = c.f; c.i = w.z & 0xffff0000u; v[5] = c.f;
    c.i = w.w << 16; v[6] = c.f; c.i = w.w & 0xffff0000u; v[7] = c.f;
}

// Wave-local sync: per-wave slabs need no s_barrier. DS ops complete in
// order within a wave; lgkmcnt(0) + scheduling barrier gives the ordering.
__device__ __forceinline__ void wsync() {
    asm volatile("s_waitcnt lgkmcnt(0)" ::: "memory");
    __builtin_amdgcn_wave_barrier();
}

// =====================================================================
// MFMA helpers (16x16x32_bf16, layouts m89/m91-verified):
//   A[m][k]: lane l holds m=l&15, k=(l>>4)*8+j
//   B[k][n]: lane l holds n=l&15, k=(l>>4)*8+j  (B operand = W row-major)
//   D[r][c]: lane l holds c=l&15, r=(l>>4)*4+reg
// 3-pass split precision: v = hi + lo (both bf16); D = al*bh + ah*bl + ah*bh
// -> fp32-equivalent GEMM error (lo*lo term ~2^-18 rel, dropped).
// =====================================================================

// Load a 64x64 fp32 weight panel's per-thread 16 floats into registers.
__device__ __forceinline__ void loadw_regs(const float* src, int rstride,
                                           float* v, int t) {
    const int row = t >> 2, seg = t & 3;
    const float* p = src + (long)row * rstride + seg * 16;
    #pragma unroll
    for (int q = 0; q < 4; ++q) *(float4*)&v[q * 4] = *(const float4*)(p + q * 4);
}

// Convert the 16 register floats to hi/lo bf16 and write to LDS (pitch 72).
__device__ __forceinline__ void writew_lds(const float* v, u16* wh, u16* wl, int t) {
    const int row = t >> 2, seg = t & 3;
    u16 hh[16], ll[16];
    #pragma unroll
    for (int j = 0; j < 16; ++j) {
        u16 hi = f2bf(v[j]);
        hh[j] = hi;
        ll[j] = f2bf(v[j] - bf2f(hi));
    }
    const int base = row * 72 + seg * 16;
    *(uint4*)&wh[base]     = *(uint4*)&hh[0];
    *(uint4*)&wh[base + 8] = *(uint4*)&hh[8];
    *(uint4*)&wl[base]     = *(uint4*)&ll[0];
    *(uint4*)&wl[base + 8] = *(uint4*)&ll[8];
}

__device__ __forceinline__ void load_a64(const float* m, int arow, int ko,
                                         bf16x8 ah[2], bf16x8 al[2]) {
    if (arow < N_NODES) {
        #pragma unroll
        for (int ks = 0; ks < 2; ++ks) {
            const float* p = m + (long)arow * 64 + ks * 32 + ko;
            float v[8];
            *(float4*)&v[0] = *(const float4*)p;
            *(float4*)&v[4] = *(const float4*)(p + 4);
            #pragma unroll
            for (int j = 0; j < 8; ++j) {
                u16 hi = f2bf(v[j]);
                ah[ks][j] = (short)hi;
                al[ks][j] = (short)f2bf(v[j] - bf2f(hi));
            }
        }
    } else {
        #pragma unroll
        for (int ks = 0; ks < 2; ++ks) { ah[ks] = (bf16x8)0; al[ks] = (bf16x8)0; }
    }
}

__device__ __forceinline__ fx4 gemm3(const bf16x8 ah[2], const bf16x8 al[2],
                                     const u16* wh, const u16* wl,
                                     int colrow, int ko) {
    fx4 acc = {0.f, 0.f, 0.f, 0.f};
    #pragma unroll
    for (int ks = 0; ks < 2; ++ks) {
        const bf16x8 bh = *(const bf16x8*)&wh[colrow * 72 + ks * 32 + ko];
        const bf16x8 bl = *(const bf16x8*)&wl[colrow * 72 + ks * 32 + ko];
        acc = MFMA16(al[ks], bh, acc);
        acc = MFMA16(ah[ks], bl, acc);
        acc = MFMA16(ah[ks], bh, acc);
    }
    return acc;
}

// =====================================================================
// proj R29: grid (157, 8) — head h per block. One A-tile staging feeds
// FOUR GEMMs: NQ (fp32), NK (bf16), NV->LDS, G = NV@Wlin_h^T (bf16).
// Weight panels double-buffered in REGISTERS: stage s+1's panel is
// loaded while stage s's GEMM runs -> the global-load latency that was
// exposed between every pair of syncs now overlaps compute (+16 VGPR).
// =====================================================================
__global__ __launch_bounds__(256) void proj_kernel(
    const float* __restrict__ x,
    const float* __restrict__ Wq, const float* __restrict__ bq,
    const float* __restrict__ Wk, const float* __restrict__ bk,
    const float* __restrict__ Wv, const float* __restrict__ bv,
    const float* __restrict__ Wlin,
    float* __restrict__ NQ, u16* __restrict__ NK, u16* __restrict__ G)
{
    __shared__ __align__(16) u16 wh[64 * 72];
    __shared__ __align__(16) u16 wl[64 * 72];
    __shared__ __align__(16) u16 nvh[4 * 16 * 72];
    __shared__ __align__(16) u16 nvl[4 * 16 * 72];

    const int t  = threadIdx.x;
    const int l  = t & 63, w = t >> 6;
    const int ko = (l >> 4) * 8;
    const int r0 = blockIdx.x * 64;
    const int h  = blockIdx.y;
    const int c0 = h * 64;

    bf16x8 ah[2], al[2];
    load_a64(x, r0 + w * 16 + (l & 15), ko, ah, al);

    float wreg[16];
    loadw_regs(Wq + (long)c0 * 64, 64, wreg, t);   // panel 0 -> regs

    fx4 acc[4];

    // ---- stage 0: Q panel (fp32 out) ----
    writew_lds(wreg, wh, wl, t);
    loadw_regs(Wk + (long)c0 * 64, 64, wreg, t);   // prefetch K panel
    __syncthreads();
    #pragma unroll
    for (int cf = 0; cf < 4; ++cf)
        acc[cf] = gemm3(ah, al, wh, wl, cf * 16 + (l & 15), ko);
    #pragma unroll
    for (int cf = 0; cf < 4; ++cf) {
        const int col = c0 + cf * 16 + (l & 15);
        const float bias = bq[col];
        #pragma unroll
        for (int j = 0; j < 4; ++j) {
            const int gr = r0 + w * 16 + (l >> 4) * 4 + j;
            if (gr < N_NODES) NQ[(long)gr * 512 + col] = acc[cf][j] + bias;
        }
    }
    __syncthreads();

    // ---- stage 1: K panel (bf16 out) ----
    writew_lds(wreg, wh, wl, t);
    loadw_regs(Wv + (long)c0 * 64, 64, wreg, t);   // prefetch V panel
    __syncthreads();
    #pragma unroll
    for (int cf = 0; cf < 4; ++cf)
        acc[cf] = gemm3(ah, al, wh, wl, cf * 16 + (l & 15), ko);
    #pragma unroll
    for (int cf = 0; cf < 4; ++cf) {
        const int col = c0 + cf * 16 + (l & 15);
        const float bias = bk[col];
        #pragma unroll
        for (int j = 0; j < 4; ++j) {
            const int gr = r0 + w * 16 + (l >> 4) * 4 + j;
            if (gr < N_NODES) NK[(long)gr * 512 + col] = f2bf(acc[cf][j] + bias);
        }
    }
    __syncthreads();

    // ---- stage 2: V panel -> LDS (hi/lo bf16, per-wave 16-row slab) ----
    writew_lds(wreg, wh, wl, t);
    loadw_regs(Wlin + c0, 512, wreg, t);           // prefetch Wlin slice
    __syncthreads();
    #pragma unroll
    for (int cf = 0; cf < 4; ++cf)
        acc[cf] = gemm3(ah, al, wh, wl, cf * 16 + (l & 15), ko);
    #pragma unroll
    for (int cf = 0; cf < 4; ++cf) {
        const int col = cf * 16 + (l & 15);
        const float bias = bv[c0 + col];
        #pragma unroll
        for (int j = 0; j < 4; ++j) {
            const int rloc = (l >> 4) * 4 + j;
            float v = acc[cf][j] + bias;
            u16 hi = f2bf(v);
            nvh[w * 1152 + rloc * 72 + col] = hi;
            nvl[w * 1152 + rloc * 72 + col] = f2bf(v - bf2f(hi));
        }
    }
    __syncthreads();   // all reads of wh/wl (V panel) complete

    // ---- stage 3: G = NV @ WlinSlice^T ----
    writew_lds(wreg, wh, wl, t);
    __syncthreads();

    bf16x8 a2h[2], a2l[2];
    #pragma unroll
    for (int ks = 0; ks < 2; ++ks) {
        a2h[ks] = *(const bf16x8*)&nvh[w * 1152 + (l & 15) * 72 + ks * 32 + ko];
        a2l[ks] = *(const bf16x8*)&nvl[w * 1152 + (l & 15) * 72 + ks * 32 + ko];
    }
    #pragma unroll
    for (int cf = 0; cf < 4; ++cf)
        acc[cf] = gemm3(a2h, a2l, wh, wl, cf * 16 + (l & 15), ko);

    #pragma unroll
    for (int cf = 0; cf < 4; ++cf) {
        const int col = c0 + cf * 16 + (l & 15);
        #pragma unroll
        for (int j = 0; j < 4; ++j) {
            const int gr = r0 + w * 16 + (l >> 4) * 4 + j;
            if (gr < N_NODES) G[(long)gr * 512 + col] = f2bf(acc[cf][j]);
        }
    }
}

// =====================================================================
// node kernel R24 (VERBATIM revert — best measured: 163.6 us total,
// no spill). 256 threads = 4 waves, ONE NODE PER WAVE.
//  - Wave-synchronous: one block barrier (after `well`); all other
//    syncs intra-wave (private slab).
//  - Slab 2272 floats -> 38528 B/block -> 4 blocks/CU = 16 waves/CU.
//  - R25-R28 lesson: ev_reg / register-path out_node / 2-nodes-per-wave
//    all exceed the register budget and spill (~100-450 MB scratch).
// =====================================================================
#define SLAB_F 2272
__global__ __launch_bounds__(256, 4) void node_kernel(
    const float* __restrict__ ef, const int* __restrict__ e1,
    const float* __restrict__ NQ, const u16* __restrict__ NK,
    const u16* __restrict__ G,
    const float* __restrict__ Weq, const float* __restrict__ beq,
    const float* __restrict__ Wev, const float* __restrict__ bev,
    const float* __restrict__ Wek, const float* __restrict__ bek,
    const float* __restrict__ Wel, const float* __restrict__ bel,
    const float* __restrict__ Wele, const float* __restrict__ bele,
    const float* __restrict__ blin,
    float* __restrict__ out_node, float* __restrict__ out_edge)
{
    __shared__ __align__(16) float well[8 * 68];           // shared across waves
    __shared__ __align__(16) float slabs[4][SLAB_F];       // per-wave

    const int t   = threadIdx.x;
    const int t64 = t & 63;
    const int wv  = t >> 6;
    const int n   = (int)__builtin_amdgcn_readfirstlane(blockIdx.x * 4 + wv);

    float* S      = slabs[wv];
    // live ranges: eq/ek/ev+sl+efl (phases 1-6) all dead before gbuf (8-9)
    float* eqb    = S;             // 544 floats, pitch 68 (eob aliases)
    float* ekb    = S + 544;
    float* evb    = S + 1088;
    float* eob    = eqb;           // alias: eq dead after phase 3
    float* sl     = S + 1632;      // 288 floats [eh][72]
    float* efl    = S + 1920;      // 128
    u16*   gbuf   = (u16*)S;       // 8 rows x pitch 520 u16 = 8320 B (0..2080f)
    float* sqk_l  = S + 2080;      // 64  (live until phase 8 -> above gbuf)
    float* emb_l  = S + 2144;      // 64
    float* attn_l = S + 2208;      // 64   (total 2272)

    // -------- phase 0: issue ALL global loads up front --------
    int tg[8];
    #pragma unroll
    for (int i = 0; i < 8; ++i) tg[i] = e1[n * 8 + i];     // uniform -> s_load

    // Q fragment: q8[j] = NQ[n*512 + t64*8 + j]  (h = t64>>3, dchunk = t64&7)
    float q8[8];
    {
        const float4* p = (const float4*)(NQ + (long)n * 512 + t64 * 8);
        *(float4*)&q8[0] = p[0];
        *(float4*)&q8[4] = p[1];
    }
    // NK gather: kreg[i] = NK[tg[i]*512 + t64*8 .. +8] (bf16, 16B)
    uint4 kreg[8];
    #pragma unroll
    for (int i = 0; i < 8; ++i)
        kreg[i] = *(const uint4*)(NK + (long)tg[i] * 512 + t64 * 8);

    float2 efv = ((const float2*)(ef + (long)n * 128))[t64];

    float wq16[16], wv16[16], wk8[8], wele8[8];
    {
        const float4* p = (const float4*)(Weq + t64 * 16);
        #pragma unroll
        for (int q4 = 0; q4 < 4; ++q4) *(float4*)&wq16[q4 * 4] = p[q4];
        const float4* q = (const float4*)(Wev + t64 * 16);
        #pragma unroll
        for (int q4 = 0; q4 < 4; ++q4) *(float4*)&wv16[q4 * 4] = q[q4];
        const float4* r = (const float4*)(Wek + t64 * 8);
        *(float4*)&wk8[0] = r[0]; *(float4*)&wk8[4] = r[1];
        const float4* s = (const float4*)(Wele + (t64 & 15) * 8);
        *(float4*)&wele8[0] = s[0]; *(float4*)&wele8[4] = s[1];
    }
    const float beqv = beq[t64], bevv = bev[t64], bekv = bek[t64];
    const float bele_t = bele[t64 & 15];
    const float blin_t = blin[t64];

    // stage well (all 256 threads) and efl (per-wave)
    #pragma unroll
    for (int rep = 0; rep < 2; ++rep) {
        const int idx = rep * 256 + t;
        well[(idx >> 6) * 68 + (idx & 63)] = Wel[idx];
    }
    efl[2 * t64] = efv.x; efl[2 * t64 + 1] = efv.y;

    // -------- phase 1: sq via butterfly (regs only) --------
    {
        float part[8];
        #pragma unroll
        for (int i = 0; i < 8; ++i) {
            float kv[8]; unpack8(kreg[i], kv);
            float s = q8[0] * kv[0] + q8[1] * kv[1] + q8[2] * kv[2] + q8[3] * kv[3]
                    + q8[4] * kv[4] + q8[5] * kv[5] + q8[6] * kv[6] + q8[7] * kv[7];
            part[i] = s;
        }
        #pragma unroll
        for (int m = 1; m <= 4; m <<= 1) {
            #pragma unroll
            for (int i = 0; i < 8; ++i) part[i] += __shfl_xor(part[i], m);
        }
        const int h8 = t64 >> 3, dc = t64 & 7;
        sqk_l[dc * 8 + h8] = part[dc] * 0.125f;   // sq[edge=dc][head=h8]
    }
    __syncthreads();   // B1 (block-wide: covers well; also efl/sqk_l)

    // -------- phase 2: edge projections -> eq/ek/ev --------
    #pragma unroll
    for (int i = 0; i < 8; ++i) {
        float aq = beqv, av = bevv;
        #pragma unroll
        for (int q = 0; q < 4; ++q) {
            float4 f = *(const float4*)&efl[i * 16 + q * 4];
            aq += f.x * wq16[q * 4] + f.y * wq16[q * 4 + 1] + f.z * wq16[q * 4 + 2] + f.w * wq16[q * 4 + 3];
            av += f.x * wv16[q * 4] + f.y * wv16[q * 4 + 1] + f.z * wv16[q * 4 + 2] + f.w * wv16[q * 4 + 3];
        }
        float ak = bekv;
        #pragma unroll
        for (int q = 0; q < 2; ++q) {
            float4 s = *(const float4*)&sqk_l[i * 8 + q * 4];
            ak += s.x * wk8[q * 4] + s.y * wk8[q * 4 + 1] + s.z * wk8[q * 4 + 2] + s.w * wk8[q * 4 + 3];
        }
        eqb[i * 68 + t64] = aq; evb[i * 68 + t64] = av; ekb[i * 68 + t64] = ak;
    }
    wsync();   // B2 (wave-local)

    // -------- phase 3: pair scores -> sl[eh][i*8+j] --------
    {
        const int i = t64 >> 3, j = t64 & 7;
        #pragma unroll
        for (int eh = 0; eh < 4; ++eh) {
            float acc = 0.f;
            #pragma unroll
            for (int q = 0; q < 4; ++q) {
                float4 a = *(const float4*)&eqb[i * 68 + eh * 16 + q * 4];
                float4 b = *(const float4*)&ekb[j * 68 + eh * 16 + q * 4];
                acc += a.x * b.x + a.y * b.y + a.z * b.z + a.w * b.w;
            }
            sl[eh * 72 + i * 8 + j] = acc * 0.25f;
        }
    }
    wsync();   // B3

    // -------- phase 4: softmax over j per (i, eh) --------
    if (t64 < 32) {
        const int i = t64 >> 2, eh = t64 & 3;
        float4 v0 = *(const float4*)&sl[eh * 72 + i * 8];
        float4 v1 = *(const float4*)&sl[eh * 72 + i * 8 + 4];
        float mx = fmaxf(fmaxf(fmaxf(v0.x, v0.y), fmaxf(v0.z, v0.w)),
                         fmaxf(fmaxf(v1.x, v1.y), fmaxf(v1.z, v1.w)));
        float e0 = __expf(v0.x - mx), e1_ = __expf(v0.y - mx);
        float e2 = __expf(v0.z - mx), e3  = __expf(v0.w - mx);
        float e4 = __expf(v1.x - mx), e5  = __expf(v1.y - mx);
        float e6 = __expf(v1.z - mx), e7  = __expf(v1.w - mx);
        float inv = 1.f / (e0 + e1_ + e2 + e3 + e4 + e5 + e6 + e7 + 1e-16f);
        float4 w0 = {e0 * inv, e1_ * inv, e2 * inv, e3 * inv};
        float4 w1 = {e4 * inv, e5 * inv, e6 * inv, e7 * inv};
        *(float4*)&sl[eh * 72 + i * 8]     = w0;
        *(float4*)&sl[eh * 72 + i * 8 + 4] = w1;
    }
    wsync();   // B4

    // -------- phase 5: PV -> eob (aliases eqb; eq dead) --------
    {
        const int eh = t64 >> 4;
        #pragma unroll
        for (int i = 0; i < 8; ++i) {
            float4 s0 = *(const float4*)&sl[eh * 72 + i * 8];
            float4 s1 = *(const float4*)&sl[eh * 72 + i * 8 + 4];
            float acc = s0.x * evb[0 * 68 + t64] + s0.y * evb[1 * 68 + t64]
                      + s0.z * evb[2 * 68 + t64] + s0.w * evb[3 * 68 + t64]
                      + s1.x * evb[4 * 68 + t64] + s1.y * evb[5 * 68 + t64]
                      + s1.z * evb[6 * 68 + t64] + s1.w * evb[7 * 68 + t64];
            eob[i * 68 + t64] = acc;
        }
    }
    wsync();   // B5

    // issue G-row gather (overlaps phases 6-8)
    uint4 greg[8];
    {
        const int i = t64 >> 3, c8 = t64 & 7;
        const uint4* gp = (const uint4*)(G + (long)tg[i] * 512);
        #pragma unroll
        for (int q = 0; q < 8; ++q) greg[q] = gp[c8 + q * 8];
    }

    // -------- phase 6: emb[i][h] --------
    {
        const int i = t64 >> 3, h = t64 & 7;
        float acc = bel[h];
        #pragma unroll
        for (int q = 0; q < 16; ++q) {
            float4 a  = *(const float4*)&eob[i * 68 + q * 4];
            float4 ww = *(const float4*)&well[h * 68 + q * 4];
            acc += a.x * ww.x + a.y * ww.y + a.z * ww.z + a.w * ww.w;
        }
        emb_l[i * 8 + h] = acc;
    }
    wsync();   // B6: region A (eq/ek/ev/eo/sl/efl) fully dead

    // -------- phase 7: out_edge --------
    #pragma unroll
    for (int rep = 0; rep < 2; ++rep) {
        const int idx = rep * 64 + t64;
        const int i = idx >> 4;
        float acc = bele_t;
        #pragma unroll
        for (int h = 0; h < 8; ++h) acc += emb_l[i * 8 + h] * wele8[h];
        out_edge[(long)n * 128 + idx] = acc;
    }

    // -------- phase 8: node attn softmax --------
    if (t64 < 8) {
        const int h = t64;
        float lg[8], mx = -1e30f;
        #pragma unroll
        for (int i = 0; i < 8; ++i) { lg[i] = emb_l[i * 8 + h] + sqk_l[i * 8 + h]; mx = fmaxf(mx, lg[i]); }
        float sum = 0.f;
        #pragma unroll
        for (int i = 0; i < 8; ++i) { float e = __expf(lg[i] - mx); attn_l[i * 8 + h] = e; sum += e; }
        float inv = 1.f / (sum + 1e-16f);
        #pragma unroll
        for (int i = 0; i < 8; ++i) attn_l[i * 8 + h] *= inv;
    }

    // stage G rows into gbuf (overlaps dead region, pitch 520 u16)
    {
        const int i = t64 >> 3, c8 = t64 & 7;
        #pragma unroll
        for (int q = 0; q < 8; ++q)
            *(uint4*)&gbuf[i * 520 + (c8 + q * 8) * 8] = greg[q];
    }
    wsync();   // B7

    // -------- phase 9: out_node --------
    {
        float acc = blin_t;
        #pragma unroll
        for (int i = 0; i < 8; ++i) {
            float4 a0 = *(const float4*)&attn_l[i * 8];
            float4 a1 = *(const float4*)&attn_l[i * 8 + 4];
            const u16* gr = &gbuf[i * 520];
            acc += a0.x * bf2f(gr[0 * 64 + t64]) + a0.y * bf2f(gr[1 * 64 + t64])
                 + a0.z * bf2f(gr[2 * 64 + t64]) + a0.w * bf2f(gr[3 * 64 + t64])
                 + a1.x * bf2f(gr[4 * 64 + t64]) + a1.y * bf2f(gr[5 * 64 + t64])
                 + a1.z * bf2f(gr[6 * 64 + t64]) + a1.w * bf2f(gr[7 * 64 + t64]);
        }
        out_node[(long)n * 64 + t64] = acc;
    }
}

extern "C" void kernel_launch(void* const* d_in, const int* in_sizes, int n_in,
                              void* d_out, int out_size, void* d_ws, size_t ws_size,
                              hipStream_t stream) {
    (void)in_sizes; (void)n_in; (void)out_size; (void)ws_size;
    const float* x    = (const float*)d_in[0];
    const float* ef   = (const float*)d_in[1];
    const float* Wq   = (const float*)d_in[2];
    const float* bq   = (const float*)d_in[3];
    const float* Wk   = (const float*)d_in[4];
    const float* bk   = (const float*)d_in[5];
    const float* Wv   = (const float*)d_in[6];
    const float* bv   = (const float*)d_in[7];
    const float* Wlin = (const float*)d_in[8];
    const float* blin = (const float*)d_in[9];
    const float* Weq  = (const float*)d_in[10];
    const float* beq  = (const float*)d_in[11];
    const float* Wev  = (const float*)d_in[12];
    const float* bev  = (const float*)d_in[13];
    const float* Wek  = (const float*)d_in[14];
    const float* bek  = (const float*)d_in[15];
    const float* Wel  = (const float*)d_in[16];
    const float* bel  = (const float*)d_in[17];
    const float* Wele = (const float*)d_in[18];
    const float* bele = (const float*)d_in[19];
    const int* edge_index = (const int*)d_in[20];
    const int* e1 = edge_index + N_EDGES;   // row1 = targets

    float* out_node = (float*)d_out;            // N x 64 fp32
    float* out_edge = (float*)d_out + 640000;   // E x 16 fp32

    // ws: NK bf16 [0,10.24MB) | G bf16 [10.24,20.48) | NQ fp32 [20.48,40.96MB)
    char* ws = (char*)d_ws;
    u16*   NK = (u16*)ws;
    u16*   G  = (u16*)(ws + 10240000);
    float* NQ = (float*)(ws + 20480000);

    proj_kernel<<<dim3(157, 8), 256, 0, stream>>>(x, Wq, bq, Wk, bk, Wv, bv, Wlin,
                                                  NQ, NK, G);
    node_kernel<<<2500, 256, 0, stream>>>(ef, e1, NQ, NK, G,
                                          Weq, beq, Wev, bev, Wek, bek,
                                          Wel, bel, Wele, bele, blin,
                                          out_node, out_edge);
}